// Round 6
// baseline (1098.041 us; speedup 1.0000x reference)
//
#include <hip/hip_runtime.h>

static constexpr int   NB      = 4;     // batches
static constexpr int   PP      = 1024;  // points per side
static constexpr int   DD      = 16;    // feature dim
static constexpr float EPSV    = 0.1f;
static constexpr float KE      = 14.42695041f;   // (1/eps) * log2(e)
static constexpr float KL      = 0.0693147181f;  // eps * ln(2)
static constexpr int   MAXIT   = 100;
static constexpr float THRESHV = 0.1f;

static constexpr int NBLK = 128;   // 32 blocks per batch group, all co-resident
static constexpr int NTHR = 1024;  // 16 waves; wave w owns rows/cols 2w,2w+1
static constexpr int GPB  = 32;    // blocks per group (halved fan-in vs R3)
static constexpr int RPB  = 32;    // rows (and cols) per block
static constexpr unsigned DONEG = 1000000u;   // "group finished" slot value

// ws layout (u32 idx) — proven 64B-stride arrival slots (128 used):
//   slot(block b)     : ws32[b*16]
//   Tslot             : ws32[4096]
//   exitf[n]          : ws32[4104+n]        (set-once, value = t_detect+1)
//   err_ws (floats)   : ws f-idx 4352 + n*128 + t   (pre-poisoned 0x7f = 3.4e38)
static constexpr int    ERR_F_OFF     = 4352;
static constexpr size_t WS_ZERO_BYTES = 4352 * 4;
static constexpr size_t ERR_BYTES     = 512 * 4;

// out_C scratch per batch (sc = out_C + n*PP*PP), valid until epilogue:
//   u_snap(t) = sc + t*PP ; v_snap(t) = sc + 131072 + t*PP   (write-once per t)
static constexpr int VSNAP_OFF = 131072;

__device__ __forceinline__ float fexp2(float v) { return __builtin_amdgcn_exp2f(v); }
__device__ __forceinline__ float flog2(float v) { return __builtin_amdgcn_logf(v); }

__device__ __forceinline__ float aload(const float* p) {
    return __hip_atomic_load(p, __ATOMIC_RELAXED, __HIP_MEMORY_SCOPE_AGENT);
}
__device__ __forceinline__ void astore(float* p, float v) {
    __hip_atomic_store(p, v, __ATOMIC_RELAXED, __HIP_MEMORY_SCOPE_AGENT);
}
__device__ __forceinline__ unsigned aloadu(const unsigned* p) {
    return __hip_atomic_load(p, __ATOMIC_RELAXED, __HIP_MEMORY_SCOPE_AGENT);
}
__device__ __forceinline__ void astoreu(unsigned* p, unsigned v) {
    __hip_atomic_store(p, v, __ATOMIC_RELAXED, __HIP_MEMORY_SCOPE_AGENT);
}
__device__ __forceinline__ float2 aload2(const float* p) {
    unsigned long long v = __hip_atomic_load((const unsigned long long*)p,
                                             __ATOMIC_RELAXED, __HIP_MEMORY_SCOPE_AGENT);
    union { unsigned long long u; float f[2]; } c; c.u = v;
    return make_float2(c.f[0], c.f[1]);
}
__device__ __forceinline__ void astore2(float* p, float a, float b) {
    union { unsigned long long u; float f[2]; } c; c.f[0] = a; c.f[1] = b;
    __hip_atomic_store((unsigned long long*)p, c.u,
                       __ATOMIC_RELAXED, __HIP_MEMORY_SCOPE_AGENT);
}

// LDS swizzle at float4 granularity: element e -> slot s=e>>2, phys slot
// P(s) = s ^ ((s>>3)&7), float addr 4*P + (e&3). Bank math (verified):
//   staging b128 writes (lane t<32, slots 8t+q): group = q^(t&7), 4 lanes/grp
//   u-LSE b128 reads  (slots 64k+l): permutation of linear, 2/bank/quarter
//   v-LSE scalar reads (e=l+64k): exactly 2 lanes/bank (free per m136)

// R3-proven fused barrier-poll + snapshot-fetch (wave 0). Lane t<32 owns
// producer block t: polls its slot for >= gen; on sight issues the 128B chunk
// loads (slot = chunk-ready flag; addresses write-once). Loads overlap the
// residual poll of stragglers; swizzled LDS write after ballot-exit.
__device__ __forceinline__ void stage_poll(const unsigned* ws32, int n,
                                           const float* src, unsigned gen,
                                           float* sbuf, int tid) {
    if (tid < 64) {
        const int t = tid & 31;
        bool got = (tid >= 32);
        const unsigned* sp = ws32 + (n * GPB + t) * 16;
        const float* cp = src + t * RPB;
        float2 d[16];
        for (;;) {
            if (!got && aloadu(sp) >= gen) {
                #pragma unroll
                for (int q = 0; q < 16; ++q) d[q] = aload2(cp + 2 * q);
                got = true;
            }
            if (__ballot(got) == ~0ull) break;
            __builtin_amdgcn_s_sleep(1);
        }
        if (tid < 32) {
            #pragma unroll
            for (int q = 0; q < 8; ++q) {
                int p = (8 * t + q) ^ (t & 7);   // P(8t+q), (8t+q)>>3 == t
                *(float4*)&sbuf[4 * p] =
                    make_float4(d[2 * q].x, d[2 * q].y, d[2 * q + 1].x, d[2 * q + 1].y);
            }
        }
    }
}

// plain slot barrier (epilogue only; 32 slots, lanes 32..63 mirror-idle)
__device__ __forceinline__ void gbar_group(unsigned* ws32, int n, int g, unsigned gen) {
    __syncthreads();
    if (threadIdx.x < 64) {
        if (threadIdx.x == 0) astoreu(ws32 + (n * GPB + g) * 16, gen);
        const unsigned* sp = ws32 + (n * GPB + (threadIdx.x & 31)) * 16;
        while (__ballot((threadIdx.x >= 32) || (aloadu(sp) >= gen)) != ~0ull)
            __builtin_amdgcn_s_sleep(1);
    }
    __syncthreads();
}

__global__ __launch_bounds__(NTHR, 4)
void sinkhorn_kernel(const float* __restrict__ x, const float* __restrict__ y,
                     const float* __restrict__ wx, const float* __restrict__ wy,
                     float* __restrict__ out, float* __restrict__ ws)
{
    __shared__ float rt[RPB * PP];   // this block's 32 C-rows (128 KB)
    __shared__ float sbuf[PP];       // u/v broadcast buffer (4 KB), XOR-swizzled
    __shared__ float cred[16];       // per-wave partials (err: 0..7, cost: 0..15)
    __shared__ int   Ts;             // chosen iteration T
    __shared__ int   s_ef;           // sampled exitf (uniform break by value)

    unsigned* ws32  = (unsigned*)ws;
    unsigned* Tslot = ws32 + 4096;
    unsigned* exitf = ws32 + 4104;
    float*    ews   = ws + ERR_F_OFF;

    float* out_cost = out;
    float* out_pi   = out + NB;
    float* out_C    = out + NB + (size_t)NB * PP * PP;

    const int b   = blockIdx.x;
    const int n   = b >> 5;            // batch / group
    const int g   = b & (GPB - 1);     // block within group
    const int i0  = g * RPB;           // first row (and col) of this block
    const int w   = threadIdx.x >> 6;  // wave 0..15
    const int l   = threadIdx.x & 63;  // lane
    const int tid = threadIdx.x;

    float* sc = out_C + (size_t)n * PP * PP;   // this batch's snapshot scratch

    if (tid == 0) s_ef = 0;

    // loop-invariant swizzled LDS addressing
    const int lx = l ^ ((l >> 3) & 7);           // u-LSE float4: &sbuf[256k+4*lx]
    int rv[16];                                  // v-LSE scalar reads, e=l+64k
    #pragma unroll
    for (int k = 0; k < 16; ++k) {
        int s = 16 * k + (l >> 2);
        int p = s ^ ((2 * k + (l >> 5)) & 7);
        rv[k] = 4 * p + (l & 3);
    }
    int ea;                                      // pair (2tid, 2tid+1), tid<512
    {
        int s = tid >> 1;
        int p = s ^ ((tid >> 4) & 7);
        ea = 4 * p + 2 * (tid & 1);
    }

    // ---------------- stage A: 32 C-rows -> LDS (wave w: rows 2w,2w+1) -------
    float4 xr[2][4];
    #pragma unroll
    for (int rr = 0; rr < 2; ++rr) {
        const float4* xp = (const float4*)(x + ((size_t)n * PP + (i0 + 2 * w + rr)) * DD);
        #pragma unroll
        for (int q = 0; q < 4; ++q) xr[rr][q] = xp[q];
    }
    #pragma unroll 4
    for (int k = 0; k < 16; ++k) {
        int j = l + 64 * k;
        const float4* yp = (const float4*)(y + ((size_t)n * PP + j) * DD);
        float4 y0 = yp[0], y1 = yp[1], y2 = yp[2], y3 = yp[3];
        #pragma unroll
        for (int rr = 0; rr < 2; ++rr) {
            float c = fabsf(xr[rr][0].x - y0.x) + fabsf(xr[rr][0].y - y0.y)
                    + fabsf(xr[rr][0].z - y0.z) + fabsf(xr[rr][0].w - y0.w)
                    + fabsf(xr[rr][1].x - y1.x) + fabsf(xr[rr][1].y - y1.y)
                    + fabsf(xr[rr][1].z - y1.z) + fabsf(xr[rr][1].w - y1.w)
                    + fabsf(xr[rr][2].x - y2.x) + fabsf(xr[rr][2].y - y2.y)
                    + fabsf(xr[rr][2].z - y2.z) + fabsf(xr[rr][2].w - y2.w)
                    + fabsf(xr[rr][3].x - y3.x) + fabsf(xr[rr][3].y - y3.y)
                    + fabsf(xr[rr][3].z - y3.z) + fabsf(xr[rr][3].w - y3.w);
            rt[(2 * w + rr) * PP + j] = c;
        }
    }

    // ---------------- stage B: 32 C-cols recomputed into registers ----------
    float4 yc[2][4];
    #pragma unroll
    for (int c = 0; c < 2; ++c) {
        const float4* yp = (const float4*)(y + ((size_t)n * PP + (i0 + 2 * w + c)) * DD);
        #pragma unroll
        for (int q = 0; q < 4; ++q) yc[c][q] = yp[q];
    }
    float2 c2[16];
    #pragma unroll 4
    for (int k = 0; k < 16; ++k) {
        const float4* xp = (const float4*)(x + ((size_t)n * PP + (l + 64 * k)) * DD);
        float4 x0 = xp[0], x1 = xp[1], x2 = xp[2], x3 = xp[3];
        float cc[2];
        #pragma unroll
        for (int c = 0; c < 2; ++c) {
            cc[c] = fabsf(x0.x - yc[c][0].x) + fabsf(x0.y - yc[c][0].y)
                  + fabsf(x0.z - yc[c][0].z) + fabsf(x0.w - yc[c][0].w)
                  + fabsf(x1.x - yc[c][1].x) + fabsf(x1.y - yc[c][1].y)
                  + fabsf(x1.z - yc[c][1].z) + fabsf(x1.w - yc[c][1].w)
                  + fabsf(x2.x - yc[c][2].x) + fabsf(x2.y - yc[c][2].y)
                  + fabsf(x2.z - yc[c][2].z) + fabsf(x2.w - yc[c][2].w)
                  + fabsf(x3.x - yc[c][3].x) + fabsf(x3.y - yc[c][3].y)
                  + fabsf(x3.z - yc[c][3].z) + fabsf(x3.w - yc[c][3].w);
        }
        c2[k] = make_float2(cc[0], cc[1]);
    }

    float lmu[2], lnu[2];
    #pragma unroll
    for (int rr = 0; rr < 2; ++rr) {
        lmu[rr] = __logf(wx[n * PP + i0 + 2 * w + rr] + 1e-8f);
        lnu[rr] = __logf(wy[n * PP + i0 + 2 * w + rr] + 1e-8f);
    }

    // per-thread previous-u pair (indices 2*tid, 2*tid+1), tid<512
    float uprev0 = 0.f, uprev1 = 0.f;

    int last_t = 0;

    // ---------------- Sinkhorn loop (R3 fused poll+fetch sync) --------------
    #pragma unroll 1
    for (int t = 0; t < MAXIT; ++t) {
        // uniform exit by VALUE (R3-proven): break at t >= ef+1
        if (t >= 2 && s_ef != 0 && t >= s_ef + 1) break;
        last_t = t;

        // ---- u-staging: v_{t-1} chunks (gated by producers' 2t arrivals)
        if (t == 0) {
            if (tid < 512) { sbuf[ea] = 0.f; sbuf[ea + 1] = 0.f; }
        } else {
            stage_poll(ws32, n, sc + VSNAP_OFF + (size_t)(t - 1) * PP,
                       (unsigned)(2 * t), sbuf, tid);
        }
        __syncthreads();

        // ---- u-phase LSE (rows 2w,2w+1)
        {
            float4 tt[2][4];
            float m0 = -3.4e38f, m1 = -3.4e38f;
            #pragma unroll
            for (int k = 0; k < 4; ++k) {
                int j = 256 * k + 4 * l;
                float4 v4 = *(const float4*)&sbuf[256 * k + 4 * lx];
                float4 ca = *(const float4*)&rt[(2 * w) * PP + j];
                float4 cb = *(const float4*)&rt[(2 * w + 1) * PP + j];
                tt[0][k] = make_float4(v4.x - ca.x, v4.y - ca.y, v4.z - ca.z, v4.w - ca.w);
                tt[1][k] = make_float4(v4.x - cb.x, v4.y - cb.y, v4.z - cb.z, v4.w - cb.w);
                m0 = fmaxf(m0, fmaxf(fmaxf(tt[0][k].x, tt[0][k].y), fmaxf(tt[0][k].z, tt[0][k].w)));
                m1 = fmaxf(m1, fmaxf(fmaxf(tt[1][k].x, tt[1][k].y), fmaxf(tt[1][k].z, tt[1][k].w)));
            }
            #pragma unroll
            for (int off = 32; off >= 1; off >>= 1) {
                m0 = fmaxf(m0, __shfl_xor(m0, off));
                m1 = fmaxf(m1, __shfl_xor(m1, off));
            }
            float s0 = 0.f, s1 = 0.f;
            #pragma unroll
            for (int k = 0; k < 4; ++k) {
                s0 += fexp2((tt[0][k].x - m0) * KE) + fexp2((tt[0][k].y - m0) * KE)
                    + fexp2((tt[0][k].z - m0) * KE) + fexp2((tt[0][k].w - m0) * KE);
                s1 += fexp2((tt[1][k].x - m1) * KE) + fexp2((tt[1][k].y - m1) * KE)
                    + fexp2((tt[1][k].z - m1) * KE) + fexp2((tt[1][k].w - m1) * KE);
            }
            #pragma unroll
            for (int off = 32; off >= 1; off >>= 1) {
                s0 += __shfl_xor(s0, off);
                s1 += __shfl_xor(s1, off);
            }
            float un0 = EPSV * lmu[0] - (m0 + KL * flog2(s0));
            float un1 = EPSV * lmu[1] - (m1 + KL * flog2(s1));
            if (l == 0) astore2(sc + (size_t)t * PP + i0 + 2 * w, un0, un1);
        }
        __syncthreads();   // drain u stores (all 16 waves) before arrival
        if (tid == 0) astoreu(ws32 + (n * GPB + g) * 16, (unsigned)(2 * t + 1));

        // ---- v-staging: full u_t (gated by producers' 2t+1 arrivals)
        stage_poll(ws32, n, sc + (size_t)t * PP, (unsigned)(2 * t + 1), sbuf, tid);
        __syncthreads();

        // ---- per-thread err vs previous u pair (bitwise-identical to R0)
        if (tid < 512) {
            float up0 = sbuf[ea], up1 = sbuf[ea + 1];
            float we = fabsf(up0 - uprev0) + fabsf(up1 - uprev1);
            uprev0 = up0; uprev1 = up1;
            #pragma unroll
            for (int off = 32; off >= 1; off >>= 1) we += __shfl_xor(we, off);
            if (l == 0) cred[w] = we;
        }
        __syncthreads();

        // ---- v-phase LSE (cols 2w,2w+1)
        {
            float tt0[16], tt1[16], m0 = -3.4e38f, m1 = -3.4e38f;
            #pragma unroll
            for (int k = 0; k < 16; ++k) {
                float uu = sbuf[rv[k]];
                tt0[k] = uu - c2[k].x;
                tt1[k] = uu - c2[k].y;
                m0 = fmaxf(m0, tt0[k]);
                m1 = fmaxf(m1, tt1[k]);
            }
            #pragma unroll
            for (int off = 32; off >= 1; off >>= 1) {
                m0 = fmaxf(m0, __shfl_xor(m0, off));
                m1 = fmaxf(m1, __shfl_xor(m1, off));
            }
            float s0 = 0.f, s1 = 0.f;
            #pragma unroll
            for (int k = 0; k < 16; ++k) {
                s0 += fexp2((tt0[k] - m0) * KE);
                s1 += fexp2((tt1[k] - m1) * KE);
            }
            #pragma unroll
            for (int off = 32; off >= 1; off >>= 1) {
                s0 += __shfl_xor(s0, off);
                s1 += __shfl_xor(s1, off);
            }
            float vn0 = EPSV * lnu[0] - (m0 + KL * flog2(s0));
            float vn1 = EPSV * lnu[1] - (m1 + KL * flog2(s1));
            if (l == 0)
                astore2(sc + VSNAP_OFF + (size_t)t * PP + i0 + 2 * w, vn0, vn1);
        }
        // deterministic batch err (fixed-order sum over waves 0..7)
        if (g == 0 && tid == 0) {
            float es = cred[0] + cred[1] + cred[2] + cred[3]
                     + cred[4] + cred[5] + cred[6] + cred[7];
            astore(ews + n * 128 + t, es);
        }

        __syncthreads();   // drain v stores + errsum before arrival
        if (tid < 64) {
            if (tid == 0) astoreu(ws32 + (n * GPB + g) * 16, (unsigned)(2 * t + 2));
            if (g == 0) {
                // off-critical-path convergence detection (unwritten = 3.4e38)
                float s1f = aload(ews + 0 * 128 + tid) + aload(ews + 1 * 128 + tid)
                          + aload(ews + 2 * 128 + tid) + aload(ews + 3 * 128 + tid);
                float s2f = aload(ews + 0 * 128 + 64 + tid) + aload(ews + 1 * 128 + 64 + tid)
                          + aload(ews + 2 * 128 + 64 + tid) + aload(ews + 3 * 128 + 64 + tid);
                unsigned long long bb = __ballot(s1f < THRESHV * (float)NB)
                                      | __ballot(s2f < THRESHV * (float)NB);
                if (bb != 0ull && tid == 0 && aloadu(exitf + n) == 0u)
                    astoreu(exitf + n, (unsigned)(t + 1));   // set-once
            }
        }
        if (tid == 0) s_ef = (int)aloadu(exitf + n);   // sample for uniform break
        __syncthreads();
        // no end-of-iteration poll: fused into next iteration's u-staging
    }

    // ---------------- post-loop: final-iteration visibility ----------------
    {
        const unsigned need = (unsigned)(2 * last_t + 2);
        if (tid < 64) {
            const unsigned* sp = ws32 + (n * GPB + (tid & 31)) * 16;
            while (__ballot((tid >= 32) || (aloadu(sp) >= need)) != ~0ull)
                __builtin_amdgcn_s_sleep(1);
        }
        __syncthreads();
    }

    // ---------------- group-done signal, T-pick ----------------
    if (g == 0 && tid == 0) astoreu(ws32 + (n * GPB) * 16, DONEG);

    if (b == 0 && tid < 64) {
        for (;;) {   // wait all 4 groups done (their err series final & drained)
            bool ok = (tid >= 4) || (aloadu(ws32 + tid * GPB * 16) >= DONEG);
            if (__ballot(ok) == ~0ull) break;
            __builtin_amdgcn_s_sleep(2);
        }
        float s1f = aload(ews + 0 * 128 + tid) + aload(ews + 1 * 128 + tid)
                  + aload(ews + 2 * 128 + tid) + aload(ews + 3 * 128 + tid);
        float s2f = aload(ews + 0 * 128 + 64 + tid) + aload(ews + 1 * 128 + 64 + tid)
                  + aload(ews + 2 * 128 + 64 + tid) + aload(ews + 3 * 128 + 64 + tid);
        unsigned long long b1 = __ballot(s1f < THRESHV * (float)NB);
        unsigned long long b2 = __ballot(s2f < THRESHV * (float)NB);
        int T = b1 ? (__ffsll((long long)b1) - 1)
                   : (b2 ? 64 + (__ffsll((long long)b2) - 1) : MAXIT - 1);
        if (tid == 0) astoreu(Tslot, (unsigned)(T + 1));
    }
    if (tid == 0) {
        unsigned tv;
        while ((tv = aloadu(Tslot)) == 0u) __builtin_amdgcn_s_sleep(2);
        Ts = (int)tv - 1;
    }
    __syncthreads();
    const int T = Ts;

    // reload snapshot T: own u pair (wave-uniform broadcast) + full v into sbuf
    // (T <= last_t of every block; visibility via the post-loop slot wait)
    float u_loc[2];
    {
        float2 up = aload2(sc + (size_t)T * PP + i0 + 2 * w);
        u_loc[0] = up.x; u_loc[1] = up.y;
        if (tid < 512) {
            float2 vp = aload2(sc + VSNAP_OFF + (size_t)T * PP + 2 * tid);
            sbuf[ea] = vp.x; sbuf[ea + 1] = vp.y;
        }
    }
    // group's snapshot reads done before C overwrites the scratch region
    gbar_group(ws32, n, g, DONEG + 1u);

    // ---------------- epilogue: write C, pi, cost ----------------
    float cacc = 0.f;
    #pragma unroll
    for (int rr = 0; rr < 2; ++rr) {
        int r = 2 * w + rr;
        int i = i0 + r;
        float un = u_loc[rr];
        #pragma unroll
        for (int k = 0; k < 4; ++k) {
            int j = 256 * k + 4 * l;
            float4 c4 = *(const float4*)&rt[r * PP + j];
            float4 v4 = *(const float4*)&sbuf[256 * k + 4 * lx];
            float4 p4;
            p4.x = fexp2((un + v4.x - c4.x) * KE);
            p4.y = fexp2((un + v4.y - c4.y) * KE);
            p4.z = fexp2((un + v4.z - c4.z) * KE);
            p4.w = fexp2((un + v4.w - c4.w) * KE);
            *(float4*)&out_pi[((size_t)n * PP + i) * PP + j] = p4;
            *(float4*)&out_C [((size_t)n * PP + i) * PP + j] = c4;
            cacc += p4.x * c4.x + p4.y * c4.y + p4.z * c4.z + p4.w * c4.w;
        }
    }
    #pragma unroll
    for (int off = 32; off >= 1; off >>= 1) cacc += __shfl_xor(cacc, off);
    if (l == 0) cred[w] = cacc;
    __syncthreads();
    if (tid == 0) {
        float s = 0.f;
        #pragma unroll
        for (int q = 0; q < 16; ++q) s += cred[q];
        atomicAdd(&out_cost[n], s);   // out_cost zeroed by memset
    }
}

extern "C" void kernel_launch(void* const* d_in, const int* in_sizes, int n_in,
                              void* d_out, int out_size, void* d_ws, size_t ws_size,
                              hipStream_t stream) {
    const float* x  = (const float*)d_in[0];
    const float* y  = (const float*)d_in[1];
    const float* wx = (const float*)d_in[2];
    const float* wy = (const float*)d_in[3];
    float* out = (float*)d_out;
    float* ws  = (float*)d_ws;

    (void)hipMemsetAsync(d_ws, 0, WS_ZERO_BYTES, stream);             // slots/Tslot/flags
    (void)hipMemsetAsync((char*)d_ws + WS_ZERO_BYTES, 0x7f, ERR_BYTES, stream); // err = 3.4e38
    (void)hipMemsetAsync(d_out, 0, NB * sizeof(float), stream);       // cost accumulators

    hipLaunchKernelGGL(sinkhorn_kernel, dim3(NBLK), dim3(NTHR), 0, stream,
                       x, y, wx, wy, out, ws);
}

// Round 7
// 880.016 us; speedup vs baseline: 1.2478x; 1.2478x over previous
//
#include <hip/hip_runtime.h>

static constexpr int   NB      = 4;     // batches
static constexpr int   PP      = 1024;  // points per side
static constexpr int   DD      = 16;    // feature dim
static constexpr float EPSV    = 0.1f;
static constexpr float KE      = 14.42695041f;   // (1/eps) * log2(e)
static constexpr float KL      = 0.0693147181f;  // eps * ln(2)
static constexpr int   MAXIT   = 100;
static constexpr float THRESHV = 0.1f;

static constexpr int NBLK = 256;   // 64 blocks per batch group (proven optimum)
static constexpr int NTHR = 512;   // 8 waves (proven optimum)
static constexpr unsigned DONEG = 1000000u;   // "group finished" slot value

// ws layout (u32 idx) — proven 64B-stride arrival slots:
//   slot(block b)     : ws32[b*16]          [0..4095]
//   Tslot             : ws32[4096]
//   exitf[n]          : ws32[4104+n]        (set-once, value = t_detect+1)
//   err_ws (floats)   : ws f-idx 4352 + n*128 + t   (pre-poisoned 0x7f = 3.4e38)
static constexpr int    ERR_F_OFF     = 4352;
static constexpr size_t WS_ZERO_BYTES = 4352 * 4;
static constexpr size_t ERR_BYTES     = 512 * 4;

// out_C scratch per batch, 64B-ALIGNED via SNAP_SHIFT (out_C is +16B off 64B;
// +48B fixes it -> each block's 16-float chunk is exactly one 64B line):
//   sc = out_C + n*PP*PP + SNAP_SHIFT
//   u_snap(t) = sc + t*PP ; v_snap(t) = sc + VSNAP_OFF + t*PP  (write-once)
static constexpr int SNAP_SHIFT = 12;
static constexpr int VSNAP_OFF  = 131072;

__device__ __forceinline__ float fexp2(float v) { return __builtin_amdgcn_exp2f(v); }
__device__ __forceinline__ float flog2(float v) { return __builtin_amdgcn_logf(v); }

__device__ __forceinline__ float aload(const float* p) {
    return __hip_atomic_load(p, __ATOMIC_RELAXED, __HIP_MEMORY_SCOPE_AGENT);
}
__device__ __forceinline__ void astore(float* p, float v) {
    __hip_atomic_store(p, v, __ATOMIC_RELAXED, __HIP_MEMORY_SCOPE_AGENT);
}
__device__ __forceinline__ unsigned aloadu(const unsigned* p) {
    return __hip_atomic_load(p, __ATOMIC_RELAXED, __HIP_MEMORY_SCOPE_AGENT);
}
__device__ __forceinline__ void astoreu(unsigned* p, unsigned v) {
    __hip_atomic_store(p, v, __ATOMIC_RELAXED, __HIP_MEMORY_SCOPE_AGENT);
}
__device__ __forceinline__ float2 aload2(const float* p) {
    unsigned long long v = __hip_atomic_load((const unsigned long long*)p,
                                             __ATOMIC_RELAXED, __HIP_MEMORY_SCOPE_AGENT);
    union { unsigned long long u; float f[2]; } c; c.u = v;
    return make_float2(c.f[0], c.f[1]);
}
__device__ __forceinline__ void astore2(float* p, float a, float b) {
    union { unsigned long long u; float f[2]; } c; c.f[0] = a; c.f[1] = b;
    __hip_atomic_store((unsigned long long*)p, c.u,
                       __ATOMIC_RELAXED, __HIP_MEMORY_SCOPE_AGENT);
}

// LDS swizzle at float4 granularity (R6-proven at conflict floor 2.3e5):
// element e -> slot s=e>>2, phys P(s) = s ^ ((s>>3)&7) (involution/bijection),
// float addr 4*P + (e&3). Verified uniform-minimal for: staging b128 writes
// (8 lanes/bank-group), u-LSE b128 reads (8/group), v-LSE scalar (2/bank).

// R3-proven fused barrier-poll + snapshot-fetch (wave 0). Lane tid<64 owns
// producer block tid: polls its slot for >= gen; on sight issues the 64B
// chunk loads (slot = chunk-ready flag; addresses write-once). Loads overlap
// the residual poll of stragglers; 4x b128 swizzled LDS write after exit.
__device__ __forceinline__ void stage_poll(const unsigned* ws32, int n,
                                           const float* src, unsigned gen,
                                           float* sbuf, int tid) {
    if (tid < 64) {
        const unsigned* sp = ws32 + (n * 64 + tid) * 16;
        const float* cp = src + tid * 16;   // one 64B-aligned line
        float2 d0, d1, d2, d3, d4, d5, d6, d7;
        bool got = false;
        for (;;) {
            if (!got && aloadu(sp) >= gen) {
                d0 = aload2(cp + 0);  d1 = aload2(cp + 2);
                d2 = aload2(cp + 4);  d3 = aload2(cp + 6);
                d4 = aload2(cp + 8);  d5 = aload2(cp + 10);
                d6 = aload2(cp + 12); d7 = aload2(cp + 14);
                got = true;
            }
            if (__ballot(got) == ~0ull) break;
            __builtin_amdgcn_s_sleep(1);
        }
        const int m = (tid >> 1) & 7;       // (4t+q)>>3 == t>>1 for q<4
        *(float4*)&sbuf[4 * ((4 * tid + 0) ^ m)] = make_float4(d0.x, d0.y, d1.x, d1.y);
        *(float4*)&sbuf[4 * ((4 * tid + 1) ^ m)] = make_float4(d2.x, d2.y, d3.x, d3.y);
        *(float4*)&sbuf[4 * ((4 * tid + 2) ^ m)] = make_float4(d4.x, d4.y, d5.x, d5.y);
        *(float4*)&sbuf[4 * ((4 * tid + 3) ^ m)] = make_float4(d6.x, d6.y, d7.x, d7.y);
    }
}

// plain slot barrier (epilogue only)
__device__ __forceinline__ void gbar_group(unsigned* ws32, int n, int g, unsigned gen) {
    __syncthreads();
    if (threadIdx.x < 64) {
        if (threadIdx.x == 0) astoreu(ws32 + (n * 64 + g) * 16, gen);
        const unsigned* sp = ws32 + (n * 64 + threadIdx.x) * 16;
        while (__ballot(aloadu(sp) >= gen) != ~0ull)
            __builtin_amdgcn_s_sleep(1);
    }
    __syncthreads();
}

__global__ __launch_bounds__(NTHR, 2)
void sinkhorn_kernel(const float* __restrict__ x, const float* __restrict__ y,
                     const float* __restrict__ wx, const float* __restrict__ wy,
                     float* __restrict__ out, float* __restrict__ ws)
{
    __shared__ float rt[16 * PP];    // this block's 16 C-rows (64 KB)
    __shared__ float sbuf[PP];       // u/v broadcast buffer (4 KB), XOR-swizzled
    __shared__ float cred[8];        // per-wave partials (err, then cost)
    __shared__ int   Ts;             // chosen iteration T
    __shared__ int   s_ef;           // sampled exitf (uniform break by value)
    __shared__ int   s_fired;        // g0: convergence detected (set-once)

    unsigned* ws32  = (unsigned*)ws;
    unsigned* Tslot = ws32 + 4096;
    unsigned* exitf = ws32 + 4104;
    float*    ews   = ws + ERR_F_OFF;

    float* out_cost = out;
    float* out_pi   = out + NB;
    float* out_C    = out + NB + (size_t)NB * PP * PP;

    const int b   = blockIdx.x;
    const int n   = b >> 6;            // batch / group
    const int g   = b & 63;            // block within group
    const int i0  = g * 16;            // first row (and col) of this block
    const int w   = threadIdx.x >> 6;  // wave 0..7
    const int l   = threadIdx.x & 63;  // lane
    const int tid = threadIdx.x;

    // 64B-aligned snapshot scratch for this batch
    float* sc = out_C + (size_t)n * PP * PP + SNAP_SHIFT;

    if (tid == 0) { s_ef = 0; s_fired = 0; }

    // loop-invariant swizzled LDS addressing
    const int lx = l ^ ((l >> 3) & 7);           // u-LSE float4: &sbuf[256k+4*lx]
    int rv[16];                                  // v-LSE scalar reads, e=l+64k
    #pragma unroll
    for (int k = 0; k < 16; ++k) {
        int s = 16 * k + (l >> 2);
        rv[k] = 4 * (s ^ ((2 * k + (l >> 5)) & 7)) + (l & 3);
    }
    int ea;                                      // pair (2tid, 2tid+1)
    {
        int s = tid >> 1;
        ea = 4 * (s ^ ((tid >> 4) & 7)) + 2 * (tid & 1);
    }

    // ---------------- stage A: 16 C-rows -> LDS ----------------
    float4 xr[2][4];
    #pragma unroll
    for (int rr = 0; rr < 2; ++rr) {
        const float4* xp = (const float4*)(x + ((size_t)n * PP + (i0 + 2 * w + rr)) * DD);
        #pragma unroll
        for (int q = 0; q < 4; ++q) xr[rr][q] = xp[q];
    }
    #pragma unroll 4
    for (int k = 0; k < 16; ++k) {
        int j = l + 64 * k;
        const float4* yp = (const float4*)(y + ((size_t)n * PP + j) * DD);
        float4 y0 = yp[0], y1 = yp[1], y2 = yp[2], y3 = yp[3];
        #pragma unroll
        for (int rr = 0; rr < 2; ++rr) {
            float c = fabsf(xr[rr][0].x - y0.x) + fabsf(xr[rr][0].y - y0.y)
                    + fabsf(xr[rr][0].z - y0.z) + fabsf(xr[rr][0].w - y0.w)
                    + fabsf(xr[rr][1].x - y1.x) + fabsf(xr[rr][1].y - y1.y)
                    + fabsf(xr[rr][1].z - y1.z) + fabsf(xr[rr][1].w - y1.w)
                    + fabsf(xr[rr][2].x - y2.x) + fabsf(xr[rr][2].y - y2.y)
                    + fabsf(xr[rr][2].z - y2.z) + fabsf(xr[rr][2].w - y2.w)
                    + fabsf(xr[rr][3].x - y3.x) + fabsf(xr[rr][3].y - y3.y)
                    + fabsf(xr[rr][3].z - y3.z) + fabsf(xr[rr][3].w - y3.w);
            rt[(2 * w + rr) * PP + j] = c;
        }
    }

    // ---------------- stage B: 16 C-cols recomputed into registers ----------------
    float4 yc[2][4];
    #pragma unroll
    for (int c = 0; c < 2; ++c) {
        const float4* yp = (const float4*)(y + ((size_t)n * PP + (i0 + 2 * w + c)) * DD);
        #pragma unroll
        for (int q = 0; q < 4; ++q) yc[c][q] = yp[q];
    }
    float2 c2[16];
    #pragma unroll 4
    for (int k = 0; k < 16; ++k) {
        const float4* xp = (const float4*)(x + ((size_t)n * PP + (l + 64 * k)) * DD);
        float4 x0 = xp[0], x1 = xp[1], x2 = xp[2], x3 = xp[3];
        float cc[2];
        #pragma unroll
        for (int c = 0; c < 2; ++c) {
            cc[c] = fabsf(x0.x - yc[c][0].x) + fabsf(x0.y - yc[c][0].y)
                  + fabsf(x0.z - yc[c][0].z) + fabsf(x0.w - yc[c][0].w)
                  + fabsf(x1.x - yc[c][1].x) + fabsf(x1.y - yc[c][1].y)
                  + fabsf(x1.z - yc[c][1].z) + fabsf(x1.w - yc[c][1].w)
                  + fabsf(x2.x - yc[c][2].x) + fabsf(x2.y - yc[c][2].y)
                  + fabsf(x2.z - yc[c][2].z) + fabsf(x2.w - yc[c][2].w)
                  + fabsf(x3.x - yc[c][3].x) + fabsf(x3.y - yc[c][3].y)
                  + fabsf(x3.z - yc[c][3].z) + fabsf(x3.w - yc[c][3].w);
        }
        c2[k] = make_float2(cc[0], cc[1]);
    }

    float lmu[2], lnu[2];
    #pragma unroll
    for (int rr = 0; rr < 2; ++rr) {
        lmu[rr] = __logf(wx[n * PP + i0 + 2 * w + rr] + 1e-8f);
        lnu[rr] = __logf(wy[n * PP + i0 + 2 * w + rr] + 1e-8f);
    }

    // per-thread previous-u pair (indices 2*tid, 2*tid+1) for the err series
    float uprev0 = 0.f, uprev1 = 0.f;

    int last_t = 0;

    // ---------------- Sinkhorn loop (R3 fused poll+fetch sync) --------------
    #pragma unroll 1
    for (int t = 0; t < MAXIT; ++t) {
        // uniform exit by VALUE (R3-proven): break at t >= ef+1
        if (t >= 2 && s_ef != 0 && t >= s_ef + 1) break;
        last_t = t;

        // ---- u-staging: v_{t-1} chunks (gated by producers' 2t arrivals)
        if (t == 0) {
            sbuf[ea] = 0.f; sbuf[ea + 1] = 0.f;
        } else {
            stage_poll(ws32, n, sc + VSNAP_OFF + (size_t)(t - 1) * PP,
                       (unsigned)(2 * t), sbuf, tid);
        }
        __syncthreads();

        // ---- u-phase LSE (swizzled float4 v reads)
        {
            float4 tt[2][4];
            float m0 = -3.4e38f, m1 = -3.4e38f;
            #pragma unroll
            for (int k = 0; k < 4; ++k) {
                int j = 256 * k + 4 * l;
                float4 v4 = *(const float4*)&sbuf[256 * k + 4 * lx];
                float4 ca = *(const float4*)&rt[(2 * w) * PP + j];
                float4 cb = *(const float4*)&rt[(2 * w + 1) * PP + j];
                tt[0][k] = make_float4(v4.x - ca.x, v4.y - ca.y, v4.z - ca.z, v4.w - ca.w);
                tt[1][k] = make_float4(v4.x - cb.x, v4.y - cb.y, v4.z - cb.z, v4.w - cb.w);
                m0 = fmaxf(m0, fmaxf(fmaxf(tt[0][k].x, tt[0][k].y), fmaxf(tt[0][k].z, tt[0][k].w)));
                m1 = fmaxf(m1, fmaxf(fmaxf(tt[1][k].x, tt[1][k].y), fmaxf(tt[1][k].z, tt[1][k].w)));
            }
            #pragma unroll
            for (int off = 32; off >= 1; off >>= 1) {
                m0 = fmaxf(m0, __shfl_xor(m0, off));
                m1 = fmaxf(m1, __shfl_xor(m1, off));
            }
            float s0 = 0.f, s1 = 0.f;
            #pragma unroll
            for (int k = 0; k < 4; ++k) {
                s0 += fexp2((tt[0][k].x - m0) * KE) + fexp2((tt[0][k].y - m0) * KE)
                    + fexp2((tt[0][k].z - m0) * KE) + fexp2((tt[0][k].w - m0) * KE);
                s1 += fexp2((tt[1][k].x - m1) * KE) + fexp2((tt[1][k].y - m1) * KE)
                    + fexp2((tt[1][k].z - m1) * KE) + fexp2((tt[1][k].w - m1) * KE);
            }
            #pragma unroll
            for (int off = 32; off >= 1; off >>= 1) {
                s0 += __shfl_xor(s0, off);
                s1 += __shfl_xor(s1, off);
            }
            float un0 = EPSV * lmu[0] - (m0 + KL * flog2(s0));
            float un1 = EPSV * lmu[1] - (m1 + KL * flog2(s1));
            if (l == 0) astore2(sc + (size_t)t * PP + i0 + 2 * w, un0, un1);
        }
        __syncthreads();   // drain u stores (vmcnt) before arrival
        if (tid == 0) astoreu(ws32 + (n * 64 + g) * 16, (unsigned)(2 * t + 1));

        // ---- v-staging: full u_t (gated by producers' 2t+1 arrivals)
        stage_poll(ws32, n, sc + (size_t)t * PP, (unsigned)(2 * t + 1), sbuf, tid);
        __syncthreads();

        // ---- per-thread err vs previous u pair (reads only; no sync needed
        //      before v-LSE: cred consumers moved after the drain sync)
        {
            float up0 = sbuf[ea], up1 = sbuf[ea + 1];
            float we = fabsf(up0 - uprev0) + fabsf(up1 - uprev1);
            uprev0 = up0; uprev1 = up1;
            #pragma unroll
            for (int off = 32; off >= 1; off >>= 1) we += __shfl_xor(we, off);
            if (l == 0) cred[w] = we;
        }

        // ---- detection loads issued EARLY (latency hides under v-LSE);
        //      ballots consumed after the drain sync (R4-proven form)
        float dl1[4], dl2[4];
        const bool do_det = (g == 0) && (tid < 64) && (s_fired == 0);
        if (do_det) {
            #pragma unroll
            for (int q = 0; q < NB; ++q) {
                dl1[q] = aload(ews + q * 128 + tid);
                dl2[q] = aload(ews + q * 128 + 64 + tid);
            }
        }

        // ---- v-phase LSE (swizzled scalar u reads)
        {
            float tt0[16], tt1[16], m0 = -3.4e38f, m1 = -3.4e38f;
            #pragma unroll
            for (int k = 0; k < 16; ++k) {
                float uu = sbuf[rv[k]];
                tt0[k] = uu - c2[k].x;
                tt1[k] = uu - c2[k].y;
                m0 = fmaxf(m0, tt0[k]);
                m1 = fmaxf(m1, tt1[k]);
            }
            #pragma unroll
            for (int off = 32; off >= 1; off >>= 1) {
                m0 = fmaxf(m0, __shfl_xor(m0, off));
                m1 = fmaxf(m1, __shfl_xor(m1, off));
            }
            float s0 = 0.f, s1 = 0.f;
            #pragma unroll
            for (int k = 0; k < 16; ++k) {
                s0 += fexp2((tt0[k] - m0) * KE);
                s1 += fexp2((tt1[k] - m1) * KE);
            }
            #pragma unroll
            for (int off = 32; off >= 1; off >>= 1) {
                s0 += __shfl_xor(s0, off);
                s1 += __shfl_xor(s1, off);
            }
            float vn0 = EPSV * lnu[0] - (m0 + KL * flog2(s0));
            float vn1 = EPSV * lnu[1] - (m1 + KL * flog2(s1));
            if (l == 0)
                astore2(sc + VSNAP_OFF + (size_t)t * PP + i0 + 2 * w, vn0, vn1);
        }

        __syncthreads();   // drain v stores; cred now visible block-wide
        if (tid < 64) {
            if (tid == 0) astoreu(ws32 + (n * 64 + g) * 16, (unsigned)(2 * t + 2));
            if (g == 0) {
                // deterministic batch err (fixed-order sum) for T-pick series
                float esl = cred[0] + cred[1] + cred[2] + cred[3]
                          + cred[4] + cred[5] + cred[6] + cred[7];
                if (tid == 0) astore(ews + n * 128 + t, esl);
                if (s_fired == 0) {
                    // consume early loads; own-group current-t term from LDS
                    float s1f = 0.f, s2f = 0.f;
                    #pragma unroll
                    for (int q = 0; q < NB; ++q) {
                        float e1 = dl1[q], e2 = dl2[q];
                        if (q == n) {
                            if (tid == t)      e1 = esl;
                            if (64 + tid == t) e2 = esl;
                        }
                        s1f += e1; s2f += e2;
                    }
                    unsigned long long bb = __ballot(s1f < THRESHV * (float)NB)
                                          | __ballot(s2f < THRESHV * (float)NB);
                    if (tid == 0 && bb != 0ull) {
                        astoreu(exitf + n, (unsigned)(t + 1));   // set-once
                        s_fired = 1;
                    }
                }
            }
        }
        if (tid == 0) s_ef = (int)aloadu(exitf + n);   // sample for uniform break
        __syncthreads();   // publish s_ef/s_fired; drains exitf+errsum stores
        // no end-of-iteration poll: fused into next iteration's u-staging
    }

    // ---------------- post-loop: final-iteration visibility ----------------
    {
        const unsigned need = (unsigned)(2 * last_t + 2);
        if (tid < 64) {
            const unsigned* sp = ws32 + (n * 64 + tid) * 16;
            while (__ballot(aloadu(sp) >= need) != ~0ull)
                __builtin_amdgcn_s_sleep(1);
        }
        __syncthreads();
    }

    // ---------------- group-done signal, T-pick ----------------
    if (g == 0 && tid == 0) astoreu(ws32 + (n * 64) * 16, DONEG);

    if (b == 0 && tid < 64) {
        for (;;) {   // wait all 4 groups done (their err series final & drained)
            bool ok = (tid >= 4) || (aloadu(ws32 + tid * 64 * 16) >= DONEG);
            if (__ballot(ok) == ~0ull) break;
            __builtin_amdgcn_s_sleep(2);
        }
        float s1f = aload(ews + 0 * 128 + tid) + aload(ews + 1 * 128 + tid)
                  + aload(ews + 2 * 128 + tid) + aload(ews + 3 * 128 + tid);
        float s2f = aload(ews + 0 * 128 + 64 + tid) + aload(ews + 1 * 128 + 64 + tid)
                  + aload(ews + 2 * 128 + 64 + tid) + aload(ews + 3 * 128 + 64 + tid);
        unsigned long long b1 = __ballot(s1f < THRESHV * (float)NB);
        unsigned long long b2 = __ballot(s2f < THRESHV * (float)NB);
        int T = b1 ? (__ffsll((long long)b1) - 1)
                   : (b2 ? 64 + (__ffsll((long long)b2) - 1) : MAXIT - 1);
        if (tid == 0) astoreu(Tslot, (unsigned)(T + 1));
    }
    if (tid == 0) {
        unsigned tv;
        while ((tv = aloadu(Tslot)) == 0u) __builtin_amdgcn_s_sleep(2);
        Ts = (int)tv - 1;
    }
    __syncthreads();
    const int T = Ts;

    // reload snapshot T: own u pair (broadcast) + full v into sbuf
    // (T <= every block's last_t; visibility via the post-loop slot wait)
    float u_loc[2];
    {
        float2 up = aload2(sc + (size_t)T * PP + i0 + 2 * w);
        u_loc[0] = up.x; u_loc[1] = up.y;
        float2 vp = aload2(sc + VSNAP_OFF + (size_t)T * PP + 2 * tid);
        sbuf[ea] = vp.x; sbuf[ea + 1] = vp.y;
    }
    // group's snapshot reads done before C overwrites the scratch region
    gbar_group(ws32, n, g, DONEG + 1u);

    // ---------------- epilogue: write C, pi, cost ----------------
    float cacc = 0.f;
    #pragma unroll
    for (int rr = 0; rr < 2; ++rr) {
        int r = 2 * w + rr;
        int i = i0 + r;
        float un = u_loc[rr];
        #pragma unroll
        for (int k = 0; k < 4; ++k) {
            int j = 256 * k + 4 * l;
            float4 c4 = *(const float4*)&rt[r * PP + j];
            float4 v4 = *(const float4*)&sbuf[256 * k + 4 * lx];
            float4 p4;
            p4.x = fexp2((un + v4.x - c4.x) * KE);
            p4.y = fexp2((un + v4.y - c4.y) * KE);
            p4.z = fexp2((un + v4.z - c4.z) * KE);
            p4.w = fexp2((un + v4.w - c4.w) * KE);
            *(float4*)&out_pi[((size_t)n * PP + i) * PP + j] = p4;
            *(float4*)&out_C [((size_t)n * PP + i) * PP + j] = c4;
            cacc += p4.x * c4.x + p4.y * c4.y + p4.z * c4.z + p4.w * c4.w;
        }
    }
    #pragma unroll
    for (int off = 32; off >= 1; off >>= 1) cacc += __shfl_xor(cacc, off);
    if (l == 0) cred[w] = cacc;
    __syncthreads();
    if (tid == 0) {
        float s = 0.f;
        #pragma unroll
        for (int q = 0; q < 8; ++q) s += cred[q];
        atomicAdd(&out_cost[n], s);   // out_cost zeroed by memset
    }
}

extern "C" void kernel_launch(void* const* d_in, const int* in_sizes, int n_in,
                              void* d_out, int out_size, void* d_ws, size_t ws_size,
                              hipStream_t stream) {
    const float* x  = (const float*)d_in[0];
    const float* y  = (const float*)d_in[1];
    const float* wx = (const float*)d_in[2];
    const float* wy = (const float*)d_in[3];
    float* out = (float*)d_out;
    float* ws  = (float*)d_ws;

    (void)hipMemsetAsync(d_ws, 0, WS_ZERO_BYTES, stream);             // slots/Tslot/flags
    (void)hipMemsetAsync((char*)d_ws + WS_ZERO_BYTES, 0x7f, ERR_BYTES, stream); // err = 3.4e38
    (void)hipMemsetAsync(d_out, 0, NB * sizeof(float), stream);       // cost accumulators

    hipLaunchKernelGGL(sinkhorn_kernel, dim3(NBLK), dim3(NTHR), 0, stream,
                       x, y, wx, wy, out, ws);
}

// Round 8
// 790.366 us; speedup vs baseline: 1.3893x; 1.1134x over previous
//
#include <hip/hip_runtime.h>

static constexpr int   NB      = 4;     // batches
static constexpr int   PP      = 1024;  // points per side
static constexpr int   DD      = 16;    // feature dim
static constexpr float EPSV    = 0.1f;
static constexpr float KE      = 14.42695041f;   // (1/eps) * log2(e)
static constexpr float KL      = 0.0693147181f;  // eps * ln(2)
static constexpr int   MAXIT   = 100;
static constexpr float THRESHV = 0.1f;

static constexpr int NBLK = 256;   // 64 blocks per batch group, all co-resident
static constexpr int NTHR = 512;   // 8 waves
static constexpr unsigned DONEG = 1000000u;   // "group finished" slot gen

// ws layout (u32 idx) — proven 64B-stride arrival slots:
//   slot(block b)     : ws32[b*16]          [0..4095]
//   Tslot             : ws32[4096]
//   exitf[n]          : ws32[4104+n]        (set-once, value = t_detect+1)
//   err_ws (floats)   : ws f-idx 4352 + n*128 + t   (pre-poisoned 0x7f = 3.4e38)
static constexpr int    ERR_F_OFF     = 4352;
static constexpr size_t WS_ZERO_BYTES = 4352 * 4;   // slots + Tslot + flags
static constexpr size_t ERR_BYTES     = 512 * 4;

// out_C scratch per batch (sc = out_C + n*PP*PP), valid until epilogue:
//   u_snap(t) = sc + t*PP ; v_snap(t) = sc + 131072 + t*PP   (write-once per t)
static constexpr int VSNAP_OFF = 131072;

__device__ __forceinline__ float fexp2(float v) { return __builtin_amdgcn_exp2f(v); }
__device__ __forceinline__ float flog2(float v) { return __builtin_amdgcn_logf(v); }

__device__ __forceinline__ float aload(const float* p) {
    return __hip_atomic_load(p, __ATOMIC_RELAXED, __HIP_MEMORY_SCOPE_AGENT);
}
__device__ __forceinline__ void astore(float* p, float v) {
    __hip_atomic_store(p, v, __ATOMIC_RELAXED, __HIP_MEMORY_SCOPE_AGENT);
}
__device__ __forceinline__ unsigned aloadu(const unsigned* p) {
    return __hip_atomic_load(p, __ATOMIC_RELAXED, __HIP_MEMORY_SCOPE_AGENT);
}
__device__ __forceinline__ void astoreu(unsigned* p, unsigned v) {
    __hip_atomic_store(p, v, __ATOMIC_RELAXED, __HIP_MEMORY_SCOPE_AGENT);
}
__device__ __forceinline__ float2 aload2(const float* p) {
    unsigned long long v = __hip_atomic_load((const unsigned long long*)p,
                                             __ATOMIC_RELAXED, __HIP_MEMORY_SCOPE_AGENT);
    union { unsigned long long u; float f[2]; } c; c.u = v;
    return make_float2(c.f[0], c.f[1]);
}
__device__ __forceinline__ void astore2(float* p, float a, float b) {
    union { unsigned long long u; float f[2]; } c; c.f[0] = a; c.f[1] = b;
    __hip_atomic_store((unsigned long long*)p, c.u,
                       __ATOMIC_RELAXED, __HIP_MEMORY_SCOPE_AGENT);
}

// LDS swizzle at float4 granularity (R6/R7-proven at conflict floor 2.3e5):
// element e -> slot s=e>>2, phys P(s) = s ^ ((s>>3)&7) (involution/bijection),
// float addr 4*P + (e&3). Bank math verified <=2-way (free) for: staging b128
// writes, u-LSE b128 reads, v-LSE scalar reads, err pair reads, epilogue.

// R3-proven fused barrier-poll + snapshot-fetch (wave 0 only). Lane tid owns
// producer block 'tid' of this group: polls its slot for >= gen, and as soon
// as it appears, issues the 64B chunk loads (slot doubles as chunk-ready flag
// — addresses are write-once, so a seen slot implies final data). Loads
// overlap the residual poll of stragglers; swizzled 4x b128 LDS write after
// ballot-exit.
__device__ __forceinline__ void stage_poll(const unsigned* ws32, int n,
                                           const float* src, unsigned gen,
                                           float* sbuf, int tid) {
    if (tid < 64) {
        const unsigned* sp = ws32 + (n * 64 + tid) * 16;
        const float* cp = src + tid * 16;
        float2 d0, d1, d2, d3, d4, d5, d6, d7;
        bool got = false;
        for (;;) {
            if (!got && aloadu(sp) >= gen) {
                d0 = aload2(cp + 0);  d1 = aload2(cp + 2);
                d2 = aload2(cp + 4);  d3 = aload2(cp + 6);
                d4 = aload2(cp + 8);  d5 = aload2(cp + 10);
                d6 = aload2(cp + 12); d7 = aload2(cp + 14);
                got = true;
            }
            if (__ballot(got) == ~0ull) break;
            __builtin_amdgcn_s_sleep(1);
        }
        const int m = (tid >> 1) & 7;       // (4t+q)>>3 == t>>1 for q<4
        *(float4*)&sbuf[4 * ((4 * tid + 0) ^ m)] = make_float4(d0.x, d0.y, d1.x, d1.y);
        *(float4*)&sbuf[4 * ((4 * tid + 1) ^ m)] = make_float4(d2.x, d2.y, d3.x, d3.y);
        *(float4*)&sbuf[4 * ((4 * tid + 2) ^ m)] = make_float4(d4.x, d4.y, d5.x, d5.y);
        *(float4*)&sbuf[4 * ((4 * tid + 3) ^ m)] = make_float4(d6.x, d6.y, d7.x, d7.y);
    }
}

// plain slot barrier (epilogue only)
__device__ __forceinline__ void gbar_group(unsigned* ws32, int n, int g, unsigned gen) {
    __syncthreads();
    if (threadIdx.x < 64) {
        if (threadIdx.x == 0) astoreu(ws32 + (n * 64 + g) * 16, gen);
        const unsigned* sp = ws32 + (n * 64 + threadIdx.x) * 16;
        while (__ballot(aloadu(sp) >= gen) != ~0ull)
            __builtin_amdgcn_s_sleep(1);
    }
    __syncthreads();
}

__global__ __launch_bounds__(NTHR, 2)
void sinkhorn_kernel(const float* __restrict__ x, const float* __restrict__ y,
                     const float* __restrict__ wx, const float* __restrict__ wy,
                     float* __restrict__ out, float* __restrict__ ws)
{
    __shared__ float rt[16 * PP];    // this block's 16 C-rows (64 KB)
    __shared__ float sbuf[PP];       // u/v broadcast buffer (4 KB), XOR-swizzled
    __shared__ float cred[8];        // per-wave partials (err, then cost)
    __shared__ int   Ts;             // chosen iteration T
    __shared__ int   s_ef;           // sampled exit flag (uniform break)

    unsigned* ws32  = (unsigned*)ws;
    unsigned* Tslot = ws32 + 4096;
    unsigned* exitf = ws32 + 4104;
    float*    ews   = ws + ERR_F_OFF;

    float* out_cost = out;
    float* out_pi   = out + NB;
    float* out_C    = out + NB + (size_t)NB * PP * PP;

    const int b   = blockIdx.x;
    const int n   = b >> 6;            // batch / group
    const int g   = b & 63;            // block within group
    const int i0  = g * 16;            // first row (and col) of this block
    const int w   = threadIdx.x >> 6;  // wave 0..7
    const int l   = threadIdx.x & 63;  // lane
    const int tid = threadIdx.x;

    float* sc = out_C + (size_t)n * PP * PP;   // this batch's snapshot scratch

    if (tid == 0) s_ef = 0;

    // loop-invariant swizzled LDS addressing
    const int lx = l ^ ((l >> 3) & 7);           // u-LSE float4: &sbuf[256k+4*lx]
    int rv[16];                                  // v-LSE scalar reads, e=l+64k
    #pragma unroll
    for (int k = 0; k < 16; ++k) {
        int s = 16 * k + (l >> 2);
        rv[k] = 4 * (s ^ ((2 * k + (l >> 5)) & 7)) + (l & 3);
    }
    int ea;                                      // pair (2tid, 2tid+1)
    {
        int s = tid >> 1;
        ea = 4 * (s ^ ((tid >> 4) & 7)) + 2 * (tid & 1);
    }

    // ---------------- stage A: 16 C-rows -> LDS ----------------
    float4 xr[2][4];
    #pragma unroll
    for (int rr = 0; rr < 2; ++rr) {
        const float4* xp = (const float4*)(x + ((size_t)n * PP + (i0 + 2 * w + rr)) * DD);
        #pragma unroll
        for (int q = 0; q < 4; ++q) xr[rr][q] = xp[q];
    }
    #pragma unroll 4
    for (int k = 0; k < 16; ++k) {
        int j = l + 64 * k;
        const float4* yp = (const float4*)(y + ((size_t)n * PP + j) * DD);
        float4 y0 = yp[0], y1 = yp[1], y2 = yp[2], y3 = yp[3];
        #pragma unroll
        for (int rr = 0; rr < 2; ++rr) {
            float c = fabsf(xr[rr][0].x - y0.x) + fabsf(xr[rr][0].y - y0.y)
                    + fabsf(xr[rr][0].z - y0.z) + fabsf(xr[rr][0].w - y0.w)
                    + fabsf(xr[rr][1].x - y1.x) + fabsf(xr[rr][1].y - y1.y)
                    + fabsf(xr[rr][1].z - y1.z) + fabsf(xr[rr][1].w - y1.w)
                    + fabsf(xr[rr][2].x - y2.x) + fabsf(xr[rr][2].y - y2.y)
                    + fabsf(xr[rr][2].z - y2.z) + fabsf(xr[rr][2].w - y2.w)
                    + fabsf(xr[rr][3].x - y3.x) + fabsf(xr[rr][3].y - y3.y)
                    + fabsf(xr[rr][3].z - y3.z) + fabsf(xr[rr][3].w - y3.w);
            rt[(2 * w + rr) * PP + j] = c;
        }
    }

    // ---------------- stage B: 16 C-cols recomputed into registers ----------------
    float4 yc[2][4];
    #pragma unroll
    for (int c = 0; c < 2; ++c) {
        const float4* yp = (const float4*)(y + ((size_t)n * PP + (i0 + 2 * w + c)) * DD);
        #pragma unroll
        for (int q = 0; q < 4; ++q) yc[c][q] = yp[q];
    }
    float2 c2[16];
    #pragma unroll 4
    for (int k = 0; k < 16; ++k) {
        const float4* xp = (const float4*)(x + ((size_t)n * PP + (l + 64 * k)) * DD);
        float4 x0 = xp[0], x1 = xp[1], x2 = xp[2], x3 = xp[3];
        float cc[2];
        #pragma unroll
        for (int c = 0; c < 2; ++c) {
            cc[c] = fabsf(x0.x - yc[c][0].x) + fabsf(x0.y - yc[c][0].y)
                  + fabsf(x0.z - yc[c][0].z) + fabsf(x0.w - yc[c][0].w)
                  + fabsf(x1.x - yc[c][1].x) + fabsf(x1.y - yc[c][1].y)
                  + fabsf(x1.z - yc[c][1].z) + fabsf(x1.w - yc[c][1].w)
                  + fabsf(x2.x - yc[c][2].x) + fabsf(x2.y - yc[c][2].y)
                  + fabsf(x2.z - yc[c][2].z) + fabsf(x2.w - yc[c][2].w)
                  + fabsf(x3.x - yc[c][3].x) + fabsf(x3.y - yc[c][3].y)
                  + fabsf(x3.z - yc[c][3].z) + fabsf(x3.w - yc[c][3].w);
        }
        c2[k] = make_float2(cc[0], cc[1]);
    }

    float lmu[2], lnu[2];
    #pragma unroll
    for (int rr = 0; rr < 2; ++rr) {
        lmu[rr] = __logf(wx[n * PP + i0 + 2 * w + rr] + 1e-8f);
        lnu[rr] = __logf(wy[n * PP + i0 + 2 * w + rr] + 1e-8f);
    }

    // per-thread previous-u pair (indices 2*tid, 2*tid+1) for the err series
    float uprev0 = 0.f, uprev1 = 0.f;

    int last_t = 0;

    // ---------------- Sinkhorn loop (R3 fused poll+fetch sync) --------------
    #pragma unroll 1
    for (int t = 0; t < MAXIT; ++t) {
        // uniform early-exit: s_ef sampled (tid0 -> LDS) at end of prev iter
        if (t >= 2 && s_ef != 0 && t >= s_ef + 1) break;
        last_t = t;

        // ---- u-staging: fetch v_{t-1} (gated by each producer's 2t arrival)
        if (t == 0) {
            sbuf[ea] = 0.f; sbuf[ea + 1] = 0.f;
        } else {
            stage_poll(ws32, n, sc + VSNAP_OFF + (size_t)(t - 1) * PP,
                       (unsigned)(2 * t), sbuf, tid);
        }
        __syncthreads();

        // ---- u-phase LSE (swizzled float4 v reads)
        {
            float4 tt[2][4];
            float m0 = -3.4e38f, m1 = -3.4e38f;
            #pragma unroll
            for (int k = 0; k < 4; ++k) {
                int j = 256 * k + 4 * l;
                float4 v4 = *(const float4*)&sbuf[256 * k + 4 * lx];
                float4 ca = *(const float4*)&rt[(2 * w) * PP + j];
                float4 cb = *(const float4*)&rt[(2 * w + 1) * PP + j];
                tt[0][k] = make_float4(v4.x - ca.x, v4.y - ca.y, v4.z - ca.z, v4.w - ca.w);
                tt[1][k] = make_float4(v4.x - cb.x, v4.y - cb.y, v4.z - cb.z, v4.w - cb.w);
                m0 = fmaxf(m0, fmaxf(fmaxf(tt[0][k].x, tt[0][k].y), fmaxf(tt[0][k].z, tt[0][k].w)));
                m1 = fmaxf(m1, fmaxf(fmaxf(tt[1][k].x, tt[1][k].y), fmaxf(tt[1][k].z, tt[1][k].w)));
            }
            #pragma unroll
            for (int off = 32; off >= 1; off >>= 1) {
                m0 = fmaxf(m0, __shfl_xor(m0, off));
                m1 = fmaxf(m1, __shfl_xor(m1, off));
            }
            float s0 = 0.f, s1 = 0.f;
            #pragma unroll
            for (int k = 0; k < 4; ++k) {
                s0 += fexp2((tt[0][k].x - m0) * KE) + fexp2((tt[0][k].y - m0) * KE)
                    + fexp2((tt[0][k].z - m0) * KE) + fexp2((tt[0][k].w - m0) * KE);
                s1 += fexp2((tt[1][k].x - m1) * KE) + fexp2((tt[1][k].y - m1) * KE)
                    + fexp2((tt[1][k].z - m1) * KE) + fexp2((tt[1][k].w - m1) * KE);
            }
            #pragma unroll
            for (int off = 32; off >= 1; off >>= 1) {
                s0 += __shfl_xor(s0, off);
                s1 += __shfl_xor(s1, off);
            }
            float un0 = EPSV * lmu[0] - (m0 + KL * flog2(s0));
            float un1 = EPSV * lmu[1] - (m1 + KL * flog2(s1));
            if (l == 0) astore2(sc + (size_t)t * PP + i0 + 2 * w, un0, un1);
        }
        __syncthreads();   // drain u stores (vmcnt) before arrival
        if (tid == 0) astoreu(ws32 + (n * 64 + g) * 16, (unsigned)(2 * t + 1));

        // ---- v-staging: fetch full u_t (gated by each producer's 2t+1 arrival)
        stage_poll(ws32, n, sc + (size_t)t * PP, (unsigned)(2 * t + 1), sbuf, tid);
        __syncthreads();

        // ---- per-thread err vs previous u pair (same mapping as baseline)
        {
            float up0 = sbuf[ea], up1 = sbuf[ea + 1];
            float we = fabsf(up0 - uprev0) + fabsf(up1 - uprev1);
            uprev0 = up0; uprev1 = up1;
            #pragma unroll
            for (int off = 32; off >= 1; off >>= 1) we += __shfl_xor(we, off);
            if (l == 0) cred[w] = we;
        }
        __syncthreads();

        // ---- v-phase LSE (swizzled scalar u reads)
        {
            float tt0[16], tt1[16], m0 = -3.4e38f, m1 = -3.4e38f;
            #pragma unroll
            for (int k = 0; k < 16; ++k) {
                float uu = sbuf[rv[k]];
                tt0[k] = uu - c2[k].x;
                tt1[k] = uu - c2[k].y;
                m0 = fmaxf(m0, tt0[k]);
                m1 = fmaxf(m1, tt1[k]);
            }
            #pragma unroll
            for (int off = 32; off >= 1; off >>= 1) {
                m0 = fmaxf(m0, __shfl_xor(m0, off));
                m1 = fmaxf(m1, __shfl_xor(m1, off));
            }
            float s0 = 0.f, s1 = 0.f;
            #pragma unroll
            for (int k = 0; k < 16; ++k) {
                s0 += fexp2((tt0[k] - m0) * KE);
                s1 += fexp2((tt1[k] - m1) * KE);
            }
            #pragma unroll
            for (int off = 32; off >= 1; off >>= 1) {
                s0 += __shfl_xor(s0, off);
                s1 += __shfl_xor(s1, off);
            }
            float vn0 = EPSV * lnu[0] - (m0 + KL * flog2(s0));
            float vn1 = EPSV * lnu[1] - (m1 + KL * flog2(s1));
            if (l == 0)
                astore2(sc + VSNAP_OFF + (size_t)t * PP + i0 + 2 * w, vn0, vn1);
        }
        // deterministic batch err (fixed-order sum)
        if (g == 0 && tid == 0) {
            float es = cred[0] + cred[1] + cred[2] + cred[3]
                     + cred[4] + cred[5] + cred[6] + cred[7];
            astore(ews + n * 128 + t, es);
        }

        __syncthreads();   // drain v stores + errsum before arrival
        if (tid < 64) {
            if (tid == 0) astoreu(ws32 + (n * 64 + g) * 16, (unsigned)(2 * t + 2));
            if (g == 0) {
                // off-critical-path convergence detection (unwritten = 3.4e38)
                float s1f = aload(ews + 0 * 128 + tid) + aload(ews + 1 * 128 + tid)
                          + aload(ews + 2 * 128 + tid) + aload(ews + 3 * 128 + tid);
                float s2f = aload(ews + 0 * 128 + 64 + tid) + aload(ews + 1 * 128 + 64 + tid)
                          + aload(ews + 2 * 128 + 64 + tid) + aload(ews + 3 * 128 + 64 + tid);
                unsigned long long bb = __ballot(s1f < THRESHV * (float)NB)
                                      | __ballot(s2f < THRESHV * (float)NB);
                if (bb != 0ull && tid == 0 && aloadu(exitf + n) == 0u)
                    astoreu(exitf + n, (unsigned)(t + 1));   // set-once
            }
        }
        if (tid == 0) s_ef = (int)aloadu(exitf + n);   // sample for uniform break
        __syncthreads();
        // no end-of-iteration poll: fused into next iteration's u-staging
    }

    // ---------------- post-loop: final-iteration visibility ----------------
    // (replaces the removed last v-barrier; all mates executed the same last_t)
    {
        const unsigned need = (unsigned)(2 * last_t + 2);
        if (tid < 64) {
            const unsigned* sp = ws32 + (n * 64 + tid) * 16;
            while (__ballot(aloadu(sp) >= need) != ~0ull)
                __builtin_amdgcn_s_sleep(1);
        }
        __syncthreads();
    }

    // ---------------- group-done signal, T-pick ----------------
    if (g == 0 && tid == 0) astoreu(ws32 + (n * 64) * 16, DONEG);

    if (b == 0 && tid < 64) {
        for (;;) {   // wait all 4 groups done (their err series final & drained)
            bool ok = (tid >= 4) || (aloadu(ws32 + tid * 64 * 16) >= DONEG);
            if (__ballot(ok) == ~0ull) break;
            __builtin_amdgcn_s_sleep(2);
        }
        float s1f = aload(ews + 0 * 128 + tid) + aload(ews + 1 * 128 + tid)
                  + aload(ews + 2 * 128 + tid) + aload(ews + 3 * 128 + tid);
        float s2f = aload(ews + 0 * 128 + 64 + tid) + aload(ews + 1 * 128 + 64 + tid)
                  + aload(ews + 2 * 128 + 64 + tid) + aload(ews + 3 * 128 + 64 + tid);
        unsigned long long b1 = __ballot(s1f < THRESHV * (float)NB);
        unsigned long long b2 = __ballot(s2f < THRESHV * (float)NB);
        int T = b1 ? (__ffsll((long long)b1) - 1)
                   : (b2 ? 64 + (__ffsll((long long)b2) - 1) : MAXIT - 1);
        if (tid == 0) astoreu(Tslot, (unsigned)(T + 1));
    }
    if (tid == 0) {
        unsigned tv;
        while ((tv = aloadu(Tslot)) == 0u) __builtin_amdgcn_s_sleep(2);
        Ts = (int)tv - 1;
    }
    __syncthreads();
    const int T = Ts;

    // reload snapshot T: own u pair (broadcast) + full v into sbuf
    float u_loc[2];
    {
        float2 up = aload2(sc + (size_t)T * PP + i0 + 2 * w);
        u_loc[0] = up.x; u_loc[1] = up.y;
        float2 vp = aload2(sc + VSNAP_OFF + (size_t)T * PP + 2 * tid);
        sbuf[ea] = vp.x; sbuf[ea + 1] = vp.y;
    }
    // group's snapshot reads done before C overwrites the scratch region
    gbar_group(ws32, n, g, DONEG + 1u);

    // ---------------- epilogue: write C, pi, cost ----------------
    float cacc = 0.f;
    #pragma unroll
    for (int rr = 0; rr < 2; ++rr) {
        int r = 2 * w + rr;
        int i = i0 + r;
        float un = u_loc[rr];
        #pragma unroll
        for (int k = 0; k < 4; ++k) {
            int j = 256 * k + 4 * l;
            float4 c4 = *(const float4*)&rt[r * PP + j];
            float4 v4 = *(const float4*)&sbuf[256 * k + 4 * lx];
            float4 p4;
            p4.x = fexp2((un + v4.x - c4.x) * KE);
            p4.y = fexp2((un + v4.y - c4.y) * KE);
            p4.z = fexp2((un + v4.z - c4.z) * KE);
            p4.w = fexp2((un + v4.w - c4.w) * KE);
            *(float4*)&out_pi[((size_t)n * PP + i) * PP + j] = p4;
            *(float4*)&out_C [((size_t)n * PP + i) * PP + j] = c4;
            cacc += p4.x * c4.x + p4.y * c4.y + p4.z * c4.z + p4.w * c4.w;
        }
    }
    #pragma unroll
    for (int off = 32; off >= 1; off >>= 1) cacc += __shfl_xor(cacc, off);
    if (l == 0) cred[w] = cacc;
    __syncthreads();
    if (tid == 0) {
        float s = 0.f;
        #pragma unroll
        for (int q = 0; q < 8; ++q) s += cred[q];
        atomicAdd(&out_cost[n], s);   // out_cost zeroed by memset
    }
}

extern "C" void kernel_launch(void* const* d_in, const int* in_sizes, int n_in,
                              void* d_out, int out_size, void* d_ws, size_t ws_size,
                              hipStream_t stream) {
    const float* x  = (const float*)d_in[0];
    const float* y  = (const float*)d_in[1];
    const float* wx = (const float*)d_in[2];
    const float* wy = (const float*)d_in[3];
    float* out = (float*)d_out;
    float* ws  = (float*)d_ws;

    (void)hipMemsetAsync(d_ws, 0, WS_ZERO_BYTES, stream);             // slots/Tslot/flags
    (void)hipMemsetAsync((char*)d_ws + WS_ZERO_BYTES, 0x7f, ERR_BYTES, stream); // err = 3.4e38
    (void)hipMemsetAsync(d_out, 0, NB * sizeof(float), stream);       // cost accumulators

    hipLaunchKernelGGL(sinkhorn_kernel, dim3(NBLK), dim3(NTHR), 0, stream,
                       x, y, wx, wy, out, ws);
}